// Round 4
// baseline (491.990 us; speedup 1.0000x reference)
//
#include <hip/hip_runtime.h>
#include <hip/hip_bf16.h>

// ComparatorNBit: A,B are [N,32] float32 in {0,1}, MSB first.
// a_eq_b = all bits equal; a_gt_b = unsigned compare of packed 32-bit words.
//
// R4: grid-stride persistent-style kernel. 3125 blocks x 256 threads; each
// block walks 10 tiles (tile = 512 float4s = 64 rows) with a 2-stage manual
// software pipeline: load tile k+1, then ballot/process tile k. Wave count
// drops 125k -> 12.5k (10x less launch/drain churn); loads stay in flight
// across the loop instead of once per short-lived wave.
// R3 post-mortem: MLP doubling + ballot was neutral (~146 us inferred);
// VALU 5%, occupancy 78%, MLP 10x over BW-latency product -> churn is the
// last untested suspect. Floor ~84 us (528 MB @ 6.3 TB/s).

__global__ void __launch_bounds__(256)
comparator_kernel(const float4* __restrict__ A, const float4* __restrict__ B,
                  float* __restrict__ out_gt, float* __restrict__ out_eq,
                  int nTiles) {
    const int tid = threadIdx.x;
    const int lane = tid & 63;

#define PACK(v) (((unsigned)((v).x > 0.5f) << 3) | ((unsigned)((v).y > 0.5f) << 2) | \
                 ((unsigned)((v).z > 0.5f) << 1) |  (unsigned)((v).w > 0.5f))

    int t = blockIdx.x;
    long long base = (long long)t * 512 + tid;
    float4 a0 = A[base], b0 = B[base];
    float4 a1 = A[base + 256], b1 = B[base + 256];

    for (;;) {
        const int tn = t + gridDim.x;
        const bool more = tn < nTiles;
        float4 na0, nb0, na1, nb1;
        if (more) {                       // block-uniform branch
            long long nb = (long long)tn * 512 + tid;
            na0 = A[nb];  nb0 = B[nb];
            na1 = A[nb + 256];  nb1 = B[nb + 256];
        }

        // ---- process current tile t ----
        unsigned an0 = PACK(a0), bn0 = PACK(b0);
        unsigned an1 = PACK(a1), bn1 = PACK(b1);

        unsigned long long d0 = __ballot(an0 != bn0);
        unsigned long long g0 = __ballot(an0 > bn0);
        unsigned long long d1 = __ballot(an1 != bn1);
        unsigned long long g1 = __ballot(an1 > bn1);

        if (lane < 16) {
            const int g = lane & 7;
            const bool second = lane >= 8;
            unsigned long long d = second ? d1 : d0;
            unsigned long long gm = second ? g1 : g0;
            unsigned db = (unsigned)(d >> (8 * g)) & 0xFFu;
            unsigned tb = (unsigned)(gm >> (8 * g)) & 0xFFu;

            // wave's chunk0 first vec = t*512 + (tid & 192); row = vec/8
            const long long row =
                (((long long)t * 512 + (tid & 192)) >> 3) + g + (second ? 32 : 0);
            unsigned msdiff = db & (0u - db);
            out_gt[row] = (tb & msdiff) ? 1.0f : 0.0f;
            out_eq[row] = (db == 0u)   ? 1.0f : 0.0f;
        }

        if (!more) break;
        t = tn;
        a0 = na0; b0 = nb0; a1 = na1; b1 = nb1;
    }
#undef PACK
}

extern "C" void kernel_launch(void* const* d_in, const int* in_sizes, int n_in,
                              void* d_out, int out_size, void* d_ws, size_t ws_size,
                              hipStream_t stream) {
    const float4* A = (const float4*)d_in[0];
    const float4* B = (const float4*)d_in[1];
    float* out = (float*)d_out;

    const int BITS = 32;
    long long n = in_sizes[0] / BITS;      // 2,000,000 rows

    float* out_gt = out;                   // output 0: a_gt_b [N]
    float* out_eq = out + n;               // output 1: a_eq_b [N]

    long long totalVec = n * 8;            // 16,000,000 float4s per input
    int nTiles = (int)((totalVec + 511) / 512);   // 31250
    int grid = 3125;                        // 10 tiles per block exactly
    comparator_kernel<<<grid, 256, 0, stream>>>(A, B, out_gt, out_eq, nTiles);
}

// Round 5
// 471.276 us; speedup vs baseline: 1.0440x; 1.0440x over previous
//
#include <hip/hip_runtime.h>
#include <hip/hip_bf16.h>

// ComparatorNBit: A,B are [N,32] float32 in {0,1}, MSB first.
// a_eq_b = all bits equal; a_gt_b = unsigned compare of packed 32-bit words.
//
// R5: best-known structure (R2: one float4/thread, one-shot 62500-block
// grid — fastest at ~133-140 us inferred) + ballot combine (R3) instead of
// the 6-deep serialized shfl chain, no bounds checks (16M vecs = grid*block
// exactly). Lane 8g+k holds nibble k (k=0 = MS nibble) of row g; ballot of
// (an!=bn)/(an>bn) gives per-row bytes; lowest set bit of the diff byte =
// most significant differing nibble.
// R4 post-mortem: persistent kernel REGRESSED (161 us measured, 3.3 TB/s
// consumption). Evidence points to a ~3.3-4 TB/s read-path cap
// (per-CU MSHR x latency, ~180 lines/CU): m13 copy = 3.15r+3.15w,
// write-only fill = 6.7 TB/s. If this round lands >=150 us kernel,
// that cap is confirmed -> roofline.

__global__ void __launch_bounds__(256)
comparator_kernel(const float4* __restrict__ A, const float4* __restrict__ B,
                  float* __restrict__ out_gt, float* __restrict__ out_eq) {
    const long long i = (long long)blockIdx.x * 256 + threadIdx.x;

    float4 a = A[i];
    float4 b = B[i];

    // Pack 4 consecutive elements into a nibble, MSB-first.
    unsigned an = ((unsigned)(a.x > 0.5f) << 3) | ((unsigned)(a.y > 0.5f) << 2) |
                  ((unsigned)(a.z > 0.5f) << 1) |  (unsigned)(a.w > 0.5f);
    unsigned bn = ((unsigned)(b.x > 0.5f) << 3) | ((unsigned)(b.y > 0.5f) << 2) |
                  ((unsigned)(b.z > 0.5f) << 1) |  (unsigned)(b.w > 0.5f);

    // Wave-wide nibble-compare masks; byte g = row g's 8 nibble results,
    // bit k within the byte = nibble k (k=0 most significant).
    unsigned long long d = __ballot(an != bn);
    unsigned long long t = __ballot(an > bn);

    const int lane = threadIdx.x & 63;
    if (lane < 16) {
        const int g = lane & 7;
        unsigned db = (unsigned)(d >> (8 * g)) & 0xFFu;
        unsigned tb = (unsigned)(t >> (8 * g)) & 0xFFu;

        // wave's first vec = blockIdx*256 + (tid & 192); row = vec/8 + g
        const long long row =
            (((long long)blockIdx.x * 256 + (threadIdx.x & 192)) >> 3) + g;

        if (lane < 8) {
            unsigned msdiff = db & (0u - db);        // lowest set bit
            out_gt[row] = (tb & msdiff) ? 1.0f : 0.0f;
        } else {
            out_eq[row] = (db == 0u) ? 1.0f : 0.0f;
        }
    }
}

extern "C" void kernel_launch(void* const* d_in, const int* in_sizes, int n_in,
                              void* d_out, int out_size, void* d_ws, size_t ws_size,
                              hipStream_t stream) {
    const float4* A = (const float4*)d_in[0];
    const float4* B = (const float4*)d_in[1];
    float* out = (float*)d_out;

    const int BITS = 32;
    long long n = in_sizes[0] / BITS;      // 2,000,000 rows

    float* out_gt = out;                   // output 0: a_gt_b [N]
    float* out_eq = out + n;               // output 1: a_eq_b [N]

    long long totalVec = n * 8;            // 16,000,000 float4s per input
    long long grid = totalVec / 256;       // 62,500 blocks, exact
    comparator_kernel<<<(int)grid, 256, 0, stream>>>(A, B, out_gt, out_eq);
}

// Round 7
// 451.289 us; speedup vs baseline: 1.0902x; 1.0443x over previous
//
#include <hip/hip_runtime.h>
#include <hip/hip_bf16.h>

// ComparatorNBit: A,B are [N,32] float32 in {0,1}, MSB first.
// a_eq_b = all bits equal; a_gt_b = unsigned compare of packed 32-bit words.
//
// R7 = R6 with the nontemporal builtin applied to a native clang vector type
// (ext_vector_type(4) float) — HIP_vector_type isn't accepted by
// __builtin_nontemporal_load. Structure unchanged from R5 (best-known:
// one float4/thread, one-shot 62500-block grid, ballot combine).
// Model under test: reads are latency x queue-depth bound (~3.3-3.9 TB/s
// effective; m13 copy read-half = 3.15 TB/s, write-only fill = 6.7 TB/s).
// Prediction: nt is NEUTRAL (confirms read-queue ceiling -> roofline at
// ~134 us kernel); <=455 us total would mean L1/L2 allocation pressure.

typedef float vfloat4 __attribute__((ext_vector_type(4)));

__global__ void __launch_bounds__(256)
comparator_kernel(const vfloat4* __restrict__ A, const vfloat4* __restrict__ B,
                  float* __restrict__ out_gt, float* __restrict__ out_eq) {
    const long long i = (long long)blockIdx.x * 256 + threadIdx.x;

    vfloat4 a = __builtin_nontemporal_load(&A[i]);
    vfloat4 b = __builtin_nontemporal_load(&B[i]);

    // Pack 4 consecutive elements into a nibble, MSB-first.
    unsigned an = ((unsigned)(a.x > 0.5f) << 3) | ((unsigned)(a.y > 0.5f) << 2) |
                  ((unsigned)(a.z > 0.5f) << 1) |  (unsigned)(a.w > 0.5f);
    unsigned bn = ((unsigned)(b.x > 0.5f) << 3) | ((unsigned)(b.y > 0.5f) << 2) |
                  ((unsigned)(b.z > 0.5f) << 1) |  (unsigned)(b.w > 0.5f);

    // Wave-wide nibble-compare masks; byte g = row g's 8 nibble results,
    // bit k within the byte = nibble k (k=0 most significant).
    unsigned long long d = __ballot(an != bn);
    unsigned long long t = __ballot(an > bn);

    const int lane = threadIdx.x & 63;
    if (lane < 16) {
        const int g = lane & 7;
        unsigned db = (unsigned)(d >> (8 * g)) & 0xFFu;
        unsigned tb = (unsigned)(t >> (8 * g)) & 0xFFu;

        // wave's first vec = blockIdx*256 + (tid & 192); row = vec/8 + g
        const long long row =
            (((long long)blockIdx.x * 256 + (threadIdx.x & 192)) >> 3) + g;

        if (lane < 8) {
            unsigned msdiff = db & (0u - db);        // lowest set bit
            __builtin_nontemporal_store((tb & msdiff) ? 1.0f : 0.0f, &out_gt[row]);
        } else {
            __builtin_nontemporal_store((db == 0u) ? 1.0f : 0.0f, &out_eq[row]);
        }
    }
}

extern "C" void kernel_launch(void* const* d_in, const int* in_sizes, int n_in,
                              void* d_out, int out_size, void* d_ws, size_t ws_size,
                              hipStream_t stream) {
    const vfloat4* A = (const vfloat4*)d_in[0];
    const vfloat4* B = (const vfloat4*)d_in[1];
    float* out = (float*)d_out;

    const int BITS = 32;
    long long n = in_sizes[0] / BITS;      // 2,000,000 rows

    float* out_gt = out;                   // output 0: a_gt_b [N]
    float* out_eq = out + n;               // output 1: a_eq_b [N]

    long long totalVec = n * 8;            // 16,000,000 float4s per input
    long long grid = totalVec / 256;       // 62,500 blocks, exact
    comparator_kernel<<<(int)grid, 256, 0, stream>>>(A, B, out_gt, out_eq);
}